// Round 2
// baseline (644.539 us; speedup 1.0000x reference)
//
#include <hip/hip_runtime.h>

// SelfAttention (Transformer-XL style) on gfx950.
// Pipeline: convert->bf16, GEMM1 8-phase (qkv), RoPE prep, flash attention, GEMM2 (dense).
// All matmuls: bf16 MFMA 16x16x32, f32 accumulate.

typedef __attribute__((ext_vector_type(4))) float f32x4;
typedef __attribute__((ext_vector_type(8))) short bf16x8;
typedef unsigned short u16;

#define SQ   1024
#define BSZ  2
#define H    4096
#define NH   32
#define HD   128
#define MEML 1024
#define KV   2048

__device__ __forceinline__ u16 f32_to_bf16(float f) {
  union { float f; unsigned int u; } v; v.f = f;
  unsigned int r = v.u + 0x7FFFu + ((v.u >> 16) & 1u);
  return (u16)(r >> 16);
}

__device__ __forceinline__ void gload_lds16(const void* g, void* l) {
  __builtin_amdgcn_global_load_lds((const __attribute__((address_space(1))) void*)g,
                                   (__attribute__((address_space(3))) void*)l, 16, 0, 0);
}

// ---------------- f32 -> bf16 convert (vectorized) ----------------
__global__ __launch_bounds__(256) void conv_bf16(const float* __restrict__ in,
                                                 u16* __restrict__ out, int n4) {
  int idx = blockIdx.x * 256 + threadIdx.x;
  if (idx < n4) {
    float4 v = ((const float4*)in)[idx];
    ushort4 o;
    o.x = f32_to_bf16(v.x); o.y = f32_to_bf16(v.y);
    o.z = f32_to_bf16(v.z); o.w = f32_to_bf16(v.w);
    ((ushort4*)out)[idx] = o;
  }
}

// ---------------- RoPE tables ----------------
__global__ __launch_bounds__(256) void rope_tables(float* __restrict__ cost, float* __restrict__ sint) {
  int idx = blockIdx.x * 256 + threadIdx.x;   // 65536 = 1024 s * 64 j
  int s = idx >> 6, j = idx & 63;
  float inv = powf(10000.0f, -(float)j / 64.0f);
  float ang = (float)(MEML + s) * inv;
  cost[idx] = cosf(ang);
  sint[idx] = sinf(ang);
}

// ---------------- 8-phase GEMM: C[M,N] = A[M,K](bf16) * B[N,K]^T(bf16) + bias[N] ----
// 256x256 tile, BK=64, 512 threads = 8 waves (2M x 4N), per-wave 128x64 out.
// Counted-vmcnt pipeline (T3+T4), setprio (T5), XOR-swizzled LDS (T2).
__global__ __launch_bounds__(512, 2) void gemm8(const u16* __restrict__ A, const u16* __restrict__ B,
                                                const float* __restrict__ bias, float* __restrict__ C,
                                                int N, int K) {
  __shared__ u16 lds[2][2][256 * 64];   // [buf][op A=0/B=1][row*64+col], 128 KiB
  const int tid = threadIdx.x;
  const int lane = tid & 63;
  const int w = tid >> 6;
  const int wm = w >> 2, wn = w & 3;
  const int rl = lane & 15, cg = lane >> 4;
  const int m0 = blockIdx.y * 256, n0 = blockIdx.x * 256;
  const int nt = K >> 6;
  const int gmax = nt << 2;

  // staging invariants: flat = i*512 + tid, row = flat>>3 (i*64 + tid>>3), slot = flat&7
  const int srow = tid >> 3;
  const int sw = ((tid & 7) << 4) ^ ((srow & 7) << 4);   // pre-swizzled source byte col
  const size_t rowPitch = (size_t)K * 2;
  const char* pAbase = (const char*)(A + (size_t)(m0 + srow) * K) + sw;
  const char* pBbase = (const char*)(B + (size_t)(n0 + srow) * K) + sw;

  auto stage = [&](int g) {
    if (g >= gmax) return;
    int tile = g >> 2, j = g & 3;
    int op = j >> 1, h = j & 1;
    const char* src = (op ? pBbase : pAbase) + (size_t)h * 128 * rowPitch + (size_t)tile * 128;
    char* dst = (char*)&lds[tile & 1][op][h * 8192] + tid * 16;
    gload_lds16(src, dst);
    gload_lds16(src + 64 * rowPitch, dst + 8192);
  };

  f32x4 acc[8][4];
#pragma unroll
  for (int i = 0; i < 8; ++i)
#pragma unroll
    for (int j = 0; j < 4; ++j) acc[i][j] = (f32x4){0.f, 0.f, 0.f, 0.f};

  bf16x8 af[4][2], bf[4][2];

  auto read_a = [&](const char* Ab, int mh) {
#pragma unroll
    for (int mi = 0; mi < 4; ++mi) {
      int ar = wm * 128 + mh * 64 + mi * 16 + rl;
#pragma unroll
      for (int kk = 0; kk < 2; ++kk) {
        int cb = (kk * 64 + cg * 16) ^ ((ar & 7) << 4);
        af[mi][kk] = *(const bf16x8*)(Ab + ar * 128 + cb);
      }
    }
  };
  auto read_b = [&](const char* Bb) {
#pragma unroll
    for (int ni = 0; ni < 4; ++ni) {
      int br = wn * 64 + ni * 16 + rl;
#pragma unroll
      for (int kk = 0; kk < 2; ++kk) {
        int cb = (kk * 64 + cg * 16) ^ ((br & 7) << 4);
        bf[ni][kk] = *(const bf16x8*)(Bb + br * 128 + cb);
      }
    }
  };
  auto mfmaq = [&](int mh, int nh) {
    __builtin_amdgcn_s_setprio(1);
#pragma unroll
    for (int kk = 0; kk < 2; ++kk)
#pragma unroll
      for (int mi = 0; mi < 4; ++mi)
#pragma unroll
        for (int ni = 0; ni < 2; ++ni)
          acc[mh * 4 + mi][nh * 2 + ni] = __builtin_amdgcn_mfma_f32_16x16x32_bf16(
              af[mi][kk], bf[nh * 2 + ni][kk], acc[mh * 4 + mi][nh * 2 + ni], 0, 0, 0);
    __builtin_amdgcn_s_setprio(0);
  };

  // prologue: tile0 {A0,A1,B0,B1}, tile1 {A0,A1}
#pragma unroll
  for (int g = 0; g < 6; ++g) stage(g);
  asm volatile("s_waitcnt vmcnt(4)" ::: "memory");
  __builtin_amdgcn_s_barrier();
  asm volatile("" ::: "memory");

  for (int kt = 0; kt < nt; ++kt) {
    const int p = kt & 1;
    const int G = 4 * kt + 6;
    const char* Ab = (const char*)lds[p][0];
    const char* Bb = (const char*)lds[p][1];
    // ---- ph0: read A(mh0) + B(all); stage (kt+1).B0 -> p^1 ----
    read_a(Ab, 0);
    read_b(Bb);
    __builtin_amdgcn_sched_barrier(0);
    stage(G + 0);
    __builtin_amdgcn_sched_barrier(0);
    __builtin_amdgcn_s_barrier();
    asm volatile("" ::: "memory");
    mfmaq(0, 0);
    __builtin_amdgcn_sched_barrier(0);
    __builtin_amdgcn_s_barrier();
    asm volatile("" ::: "memory");
    // ---- ph1: stage (kt+1).B1 -> p^1; mfma; then read A(mh1), fence reads of p ----
    stage(G + 1);
    __builtin_amdgcn_sched_barrier(0);
    __builtin_amdgcn_s_barrier();
    asm volatile("" ::: "memory");
    mfmaq(0, 1);
    __builtin_amdgcn_sched_barrier(0);
    read_a(Ab, 1);
    asm volatile("s_waitcnt lgkmcnt(0)" ::: "memory");   // all reads of buf p done (WAR safety)
    __builtin_amdgcn_sched_barrier(0);
    __builtin_amdgcn_s_barrier();
    asm volatile("" ::: "memory");
    // ---- ph2: stage (kt+2).A0 -> p (region free now) ----
    stage(G + 2);
    __builtin_amdgcn_sched_barrier(0);
    __builtin_amdgcn_s_barrier();
    asm volatile("" ::: "memory");
    mfmaq(1, 0);
    __builtin_amdgcn_sched_barrier(0);
    __builtin_amdgcn_s_barrier();
    asm volatile("" ::: "memory");
    // ---- ph3: stage (kt+2).A1 -> p; counted vmcnt covers tile kt+1 ----
    stage(G + 3);
    if (G + 3 < gmax)      { asm volatile("s_waitcnt vmcnt(4)" ::: "memory"); }
    else if (G + 2 < gmax) { asm volatile("s_waitcnt vmcnt(2)" ::: "memory"); }
    else                   { asm volatile("s_waitcnt vmcnt(0)" ::: "memory"); }
    __builtin_amdgcn_sched_barrier(0);
    __builtin_amdgcn_s_barrier();
    asm volatile("" ::: "memory");
    mfmaq(1, 1);
    __builtin_amdgcn_sched_barrier(0);
    __builtin_amdgcn_s_barrier();
    asm volatile("" ::: "memory");
  }

  // epilogue: C layout col=lane&15, row=(lane>>4)*4+j
#pragma unroll
  for (int ni = 0; ni < 4; ++ni) {
    int col = n0 + wn * 64 + ni * 16 + rl;
    float bv = bias[col];
#pragma unroll
    for (int mi = 0; mi < 8; ++mi) {
      int rbase = m0 + wm * 128 + mi * 16 + cg * 4;
#pragma unroll
      for (int j = 0; j < 4; ++j)
        C[(size_t)(rbase + j) * N + col] = acc[mi][ni][j] + bv;
    }
  }
}

// ---------------- prep: roped Q (scaled 1/sqrt(HD)) and roped new-K ----------------
__global__ __launch_bounds__(256) void prep_qk(const float* __restrict__ mixed,
                                               const float* __restrict__ cost,
                                               const float* __restrict__ sint,
                                               u16* __restrict__ Qb, u16* __restrict__ Kb) {
  int s0 = blockIdx.x * 64, head = blockIdx.y;
  int b = head >> 5, nh = head & 31;
  int tid = threadIdx.x;
  const float qs = 0.08838834764831845f;  // 1/sqrt(128)
#pragma unroll
  for (int i = 0; i < 16; ++i) {
    int flat = i * 256 + tid;    // 4096 = 64 s * 64 j
    int sl = flat >> 6, j = flat & 63;
    int s = s0 + sl;
    size_t base = ((size_t)(s * 2 + b)) * 12288 + (size_t)nh * 384;
    float q1 = mixed[base + j],       q2 = mixed[base + j + 64];
    float k1 = mixed[base + 128 + j], k2 = mixed[base + 192 + j];
    float c = cost[s * 64 + j], sn = sint[s * 64 + j];
    float q1r = q1 * c - q2 * sn, q2r = q2 * c + q1 * sn;
    float k1r = k1 * c - k2 * sn, k2r = k2 * c + k1 * sn;
    size_t qoff = ((size_t)head * SQ + s) * HD;
    Qb[qoff + j]      = f32_to_bf16(q1r * qs);
    Qb[qoff + j + 64] = f32_to_bf16(q2r * qs);
    size_t koff = ((size_t)head * KV + MEML + s) * HD;
    Kb[koff + j]      = f32_to_bf16(k1r);
    Kb[koff + j + 64] = f32_to_bf16(k2r);
  }
}

// ---------------- prep: mem-K copy + V (mem & new) transposed per head ----------------
__global__ __launch_bounds__(256) void prep_kv(const float* __restrict__ mixed,
                                               const float* __restrict__ mem,
                                               u16* __restrict__ Kb, u16* __restrict__ Vtb) {
  int t0 = blockIdx.x * 64, head = blockIdx.y;
  int b = head >> 5, nh = head & 31;
  __shared__ u16 vt[128 * 72];
  int tid = threadIdx.x;
  if (t0 < MEML) {
#pragma unroll
    for (int i = 0; i < 32; ++i) {
      int flat = i * 256 + tid;
      int tl = flat >> 7, d = flat & 127;
      float kvv = mem[((size_t)b * MEML + t0 + tl) * 8192 + (size_t)nh * HD + d];
      Kb[((size_t)head * KV + t0 + tl) * HD + d] = f32_to_bf16(kvv);
    }
  }
#pragma unroll
  for (int i = 0; i < 32; ++i) {
    int flat = i * 256 + tid;
    int tl = flat >> 7, d = flat & 127;
    int t = t0 + tl;
    float v;
    if (t < MEML) v = mem[((size_t)b * MEML + t) * 8192 + 4096 + (size_t)nh * HD + d];
    else          v = mixed[((size_t)((t - MEML) * 2 + b)) * 12288 + (size_t)nh * 384 + 256 + d];
    vt[d * 72 + tl] = f32_to_bf16(v);
  }
  __syncthreads();
#pragma unroll
  for (int i = 0; i < 4; ++i) {
    int c = i * 256 + tid;
    int d = c >> 3, slot = c & 7;
    *(bf16x8*)(Vtb + ((size_t)head * HD + d) * KV + t0 + slot * 8) =
        *(const bf16x8*)(vt + d * 72 + slot * 8);
  }
}

// ---------------- flash attention ----------------
__global__ __launch_bounds__(256) void attn_fwd(const u16* __restrict__ Qb, const u16* __restrict__ Kb,
                                                const u16* __restrict__ Vtb, u16* __restrict__ ctx) {
  __shared__ u16 Ks[64 * 128];
  __shared__ u16 Vts[128 * 64];
  __shared__ u16 Ps[4 * 16 * 64];
  const int tid = threadIdx.x;
  const int lane = tid & 63;
  const int w = tid >> 6;
  const int q0 = blockIdx.x * 64;
  const int head = blockIdx.y;
  const int rl = lane & 15, cg = lane >> 4;

  bf16x8 qf[4];
  {
    const u16* Qrow = Qb + ((size_t)head * SQ + q0 + w * 16 + rl) * HD;
#pragma unroll
    for (int kk = 0; kk < 4; ++kk)
      qf[kk] = *(const bf16x8*)(Qrow + kk * 32 + cg * 8);
  }

  f32x4 acc[8];
#pragma unroll
  for (int i = 0; i < 8; ++i) acc[i] = (f32x4){0.f, 0.f, 0.f, 0.f};
  float mrow[4] = {-3.0e38f, -3.0e38f, -3.0e38f, -3.0e38f};
  float lrow[4] = {0.f, 0.f, 0.f, 0.f};

  const int t_end = q0 + 64 + MEML;

  for (int t0 = 0; t0 < t_end; t0 += 64) {
#pragma unroll
    for (int i = 0; i < 4; ++i) {
      int flat = i * 256 + tid;
      int row = flat >> 4;
      int cb = (flat & 15) << 4;
      int scb = cb ^ ((row & 7) << 4);
      gload_lds16((const char*)(Kb + ((size_t)head * KV + t0 + row) * HD) + scb,
                  (char*)Ks + (flat << 4));
    }
#pragma unroll
    for (int i = 0; i < 4; ++i) {
      int flat = i * 256 + tid;
      int row = flat >> 3;
      int cb = (flat & 7) << 4;
      int scb = cb ^ ((row & 7) << 4);
      gload_lds16((const char*)(Vtb + ((size_t)head * HD + row) * KV + t0) + scb,
                  (char*)Vts + (flat << 4));
    }
    __syncthreads();

    f32x4 sf[4];
#pragma unroll
    for (int tn = 0; tn < 4; ++tn) {
      f32x4 s = (f32x4){0.f, 0.f, 0.f, 0.f};
#pragma unroll
      for (int kk = 0; kk < 4; ++kk) {
        int row = tn * 16 + rl;
        int cb = (kk * 64 + cg * 16) ^ ((row & 7) << 4);
        bf16x8 kf = *(const bf16x8*)((const char*)Ks + row * 256 + cb);
        s = __builtin_amdgcn_mfma_f32_16x16x32_bf16(qf[kk], kf, s, 0, 0, 0);
      }
      sf[tn] = s;
    }
    if (t0 + 63 > MEML + q0 + w * 16) {
#pragma unroll
      for (int tn = 0; tn < 4; ++tn)
#pragma unroll
        for (int j = 0; j < 4; ++j) {
          int t = t0 + tn * 16 + rl;
          int srow = q0 + w * 16 + cg * 4 + j;
          if (t - MEML > srow) sf[tn][j] = -40000.0f;
        }
    }
    float mt[4];
#pragma unroll
    for (int j = 0; j < 4; ++j)
      mt[j] = fmaxf(fmaxf(sf[0][j], sf[1][j]), fmaxf(sf[2][j], sf[3][j]));
#pragma unroll
    for (int off = 1; off <= 8; off <<= 1)
#pragma unroll
      for (int j = 0; j < 4; ++j) mt[j] = fmaxf(mt[j], __shfl_xor(mt[j], off, 64));
    float pscale[4];
#pragma unroll
    for (int j = 0; j < 4; ++j) {
      float mn = fmaxf(mrow[j], mt[j]);
      pscale[j] = __expf(mrow[j] - mn);
      mrow[j] = mn;
    }
    float lsum[4] = {0.f, 0.f, 0.f, 0.f};
#pragma unroll
    for (int tn = 0; tn < 4; ++tn)
#pragma unroll
      for (int j = 0; j < 4; ++j) {
        float p = __expf(sf[tn][j] - mrow[j]);
        lsum[j] += p;
        int prow = cg * 4 + j;
        int colb = (tn * 16 + rl) * 2;
        int addr = w * 2048 + prow * 128 + (colb ^ ((prow & 7) << 4));
        *(u16*)((char*)Ps + addr) = f32_to_bf16(p);
      }
#pragma unroll
    for (int off = 1; off <= 8; off <<= 1)
#pragma unroll
      for (int j = 0; j < 4; ++j) lsum[j] += __shfl_xor(lsum[j], off, 64);
#pragma unroll
    for (int j = 0; j < 4; ++j) lrow[j] = lrow[j] * pscale[j] + lsum[j];
#pragma unroll
    for (int dn = 0; dn < 8; ++dn)
#pragma unroll
      for (int j = 0; j < 4; ++j) acc[dn][j] *= pscale[j];
#pragma unroll
    for (int dn = 0; dn < 8; ++dn) {
#pragma unroll
      for (int kk2 = 0; kk2 < 2; ++kk2) {
        int pcb = (kk2 * 64 + cg * 16) ^ ((rl & 7) << 4);
        bf16x8 pf = *(const bf16x8*)((const char*)Ps + w * 2048 + rl * 128 + pcb);
        int vrow = dn * 16 + rl;
        int vcb = (kk2 * 64 + cg * 16) ^ ((vrow & 7) << 4);
        bf16x8 vf = *(const bf16x8*)((const char*)Vts + vrow * 128 + vcb);
        acc[dn] = __builtin_amdgcn_mfma_f32_16x16x32_bf16(pf, vf, acc[dn], 0, 0, 0);
      }
    }
    __syncthreads();
  }
  const int b = head >> 5, nh = head & 31;
#pragma unroll
  for (int dn = 0; dn < 8; ++dn)
#pragma unroll
    for (int j = 0; j < 4; ++j) {
      int srow = q0 + w * 16 + cg * 4 + j;
      float v = acc[dn][j] / lrow[j];
      ctx[((size_t)(srow * 2 + b)) * H + (size_t)nh * HD + dn * 16 + rl] = f32_to_bf16(v);
    }
}

// ---------------- launch ----------------
extern "C" void kernel_launch(void* const* d_in, const int* in_sizes, int n_in,
                              void* d_out, int out_size, void* d_ws, size_t ws_size,
                              hipStream_t stream) {
  const float* hidden  = (const float*)d_in[0];
  const float* mem     = (const float*)d_in[3];
  const float* qkv_w   = (const float*)d_in[4];
  const float* qkv_b   = (const float*)d_in[5];
  const float* dense_w = (const float*)d_in[6];
  const float* dense_b = (const float*)d_in[7];
  float* out = (float*)d_out;
  char* ws = (char*)d_ws;

  float* mixed = (float*)ws;                      // 100,663,296 B (2048x12288 f32)
  char* R1 = ws + 100663296;
  u16* hid_bf = (u16*)R1;                         // aliased: pre-GEMM1 use
  u16* qw_bf  = (u16*)(R1 + 16777216);
  u16* Qb  = (u16*)R1;
  u16* Kb  = (u16*)(R1 + 16777216);
  u16* Vtb = (u16*)(R1 + 50331648);
  u16* ctx = (u16*)(R1 + 83886080);
  u16* dw_bf = (u16*)(R1 + 100663296);
  float* cost = (float*)(ws + 234881024);
  float* sint = (float*)(ws + 234881024 + 262144);

  conv_bf16<<<8192, 256, 0, stream>>>(hidden, hid_bf, 2097152);
  conv_bf16<<<49152, 256, 0, stream>>>(qkv_w, qw_bf, 12582912);
  rope_tables<<<256, 256, 0, stream>>>(cost, sint);
  gemm8<<<dim3(48, 8), 512, 0, stream>>>(hid_bf, qw_bf, qkv_b, mixed, 12288, 4096);
  prep_qk<<<dim3(16, 64), 256, 0, stream>>>(mixed, cost, sint, Qb, Kb);
  prep_kv<<<dim3(32, 64), 256, 0, stream>>>(mixed, mem, Kb, Vtb);
  conv_bf16<<<16384, 256, 0, stream>>>(dense_w, dw_bf, 4194304);
  attn_fwd<<<dim3(16, 64), 256, 0, stream>>>(Qb, Kb, Vtb, ctx);
  gemm8<<<dim3(16, 8), 512, 0, stream>>>(ctx, dw_bf, dense_b, out, 4096, 4096);
}

// Round 3
// 633.094 us; speedup vs baseline: 1.0181x; 1.0181x over previous
//
#include <hip/hip_runtime.h>

// SelfAttention (Transformer-XL style) on gfx950.
// Pipeline: convert->bf16, GEMM (m201-style 8-phase, BM128xBN256), RoPE prep,
// flash attention, dense GEMM. All matmuls bf16 MFMA 16x16x32, f32 accumulate.

typedef __attribute__((ext_vector_type(4))) float f32x4;
typedef __attribute__((ext_vector_type(8))) short bf16x8;
typedef unsigned short u16;

#define SQ   1024
#define BSZ  2
#define H    4096
#define NH   32
#define HD   128
#define MEML 1024
#define KV   2048

__device__ __forceinline__ u16 f32_to_bf16(float f) {
  union { float f; unsigned int u; } v; v.f = f;
  unsigned int r = v.u + 0x7FFFu + ((v.u >> 16) & 1u);
  return (u16)(r >> 16);
}

__device__ __forceinline__ void gload_lds16(const void* g, void* l) {
  __builtin_amdgcn_global_load_lds((const __attribute__((address_space(1))) void*)g,
                                   (__attribute__((address_space(3))) void*)l, 16, 0, 0);
}

// ---------------- f32 -> bf16 convert (vectorized) ----------------
__global__ __launch_bounds__(256) void conv_bf16(const float* __restrict__ in,
                                                 u16* __restrict__ out, int n4) {
  int idx = blockIdx.x * 256 + threadIdx.x;
  if (idx < n4) {
    float4 v = ((const float4*)in)[idx];
    ushort4 o;
    o.x = f32_to_bf16(v.x); o.y = f32_to_bf16(v.y);
    o.z = f32_to_bf16(v.z); o.w = f32_to_bf16(v.w);
    ((ushort4*)out)[idx] = o;
  }
}

// ---------------- RoPE tables ----------------
__global__ __launch_bounds__(256) void rope_tables(float* __restrict__ cost, float* __restrict__ sint) {
  int idx = blockIdx.x * 256 + threadIdx.x;   // 65536 = 1024 s * 64 j
  int s = idx >> 6, j = idx & 63;
  float inv = powf(10000.0f, -(float)j / 64.0f);
  float ang = (float)(MEML + s) * inv;
  cost[idx] = cosf(ang);
  sint[idx] = sinf(ang);
}

// ---------------- 8-phase GEMM: C[M,N] = A[M,K](bf16) * B[N,K]^T(bf16) + bias[N] ----
// BM=128, BN=256, BK=64; 512 threads = 8 waves (2M x 4N), per-wave 64x64 out.
// 2 phases / K-tile, 16 MFMA each; counted vmcnt(2); LDS 96 KiB dbuf; T2 swizzle; T5.
__global__ __launch_bounds__(512, 2) void gemm8(const u16* __restrict__ A, const u16* __restrict__ B,
                                                const float* __restrict__ bias, float* __restrict__ C,
                                                int N, int K) {
  __shared__ char lds[2][49152];   // per buf: A 128x128B @0, B 256x128B @16384
  const int tid = threadIdx.x;
  const int lane = tid & 63;
  const int w = tid >> 6;
  const int wm = w >> 2, wn = w & 3;
  const int rl = lane & 15, cg = lane >> 4;
  const int m0 = blockIdx.y * 128, n0 = blockIdx.x * 256;
  const int nt = K >> 6;

  // staging: unit = 64 rows x 128B = 8 KiB = 1 x 16B load/thread
  const int srow = tid >> 3;                              // 0..63
  const int sw = ((tid & 7) << 4) ^ ((srow & 7) << 4);    // pre-swizzled src byte col
  const size_t rowPitch = (size_t)K * 2;
  const char* pAbase = (const char*)(A + (size_t)(m0 + srow) * K) + sw;
  const char* pBbase = (const char*)(B + (size_t)(n0 + srow) * K) + sw;

  // unit u: 0,1 = A halves (rows u*64); 2..5 = B quarters (rows (u-2)*64)
  auto stage = [&](int tile, int u) {
    if (tile >= nt) return;
    char* bufb = lds[tile & 1];
    const char* src;
    char* dst;
    if (u < 2) {
      src = pAbase + (size_t)u * 64 * rowPitch + (size_t)tile * 128;
      dst = bufb + u * 8192 + tid * 16;
    } else {
      src = pBbase + (size_t)(u - 2) * 64 * rowPitch + (size_t)tile * 128;
      dst = bufb + 16384 + (u - 2) * 8192 + tid * 16;
    }
    gload_lds16(src, dst);
  };

  f32x4 acc[4][4];
#pragma unroll
  for (int i = 0; i < 4; ++i)
#pragma unroll
    for (int j = 0; j < 4; ++j) acc[i][j] = (f32x4){0.f, 0.f, 0.f, 0.f};

  bf16x8 af[4][2], bfr[2][2];

  auto read_a = [&](const char* bufb) {
#pragma unroll
    for (int mi = 0; mi < 4; ++mi) {
      int ar = wm * 64 + mi * 16 + rl;
#pragma unroll
      for (int kk = 0; kk < 2; ++kk) {
        int cb = (kk * 64 + cg * 16) ^ ((ar & 7) << 4);
        af[mi][kk] = *(const bf16x8*)(bufb + ar * 128 + cb);
      }
    }
  };
  auto read_b = [&](const char* bufb, int nh) {
#pragma unroll
    for (int nl = 0; nl < 2; ++nl) {
      int br = wn * 64 + (nh * 2 + nl) * 16 + rl;
#pragma unroll
      for (int kk = 0; kk < 2; ++kk) {
        int cb = (kk * 64 + cg * 16) ^ ((br & 7) << 4);
        bfr[nl][kk] = *(const bf16x8*)(bufb + 16384 + br * 128 + cb);
      }
    }
  };
  auto mfmaq = [&](int nh) {
    __builtin_amdgcn_s_setprio(1);
#pragma unroll
    for (int kk = 0; kk < 2; ++kk)
#pragma unroll
      for (int mi = 0; mi < 4; ++mi)
#pragma unroll
        for (int nl = 0; nl < 2; ++nl)
          acc[mi][nh * 2 + nl] = __builtin_amdgcn_mfma_f32_16x16x32_bf16(
              af[mi][kk], bfr[nl][kk], acc[mi][nh * 2 + nl], 0, 0, 0);
    __builtin_amdgcn_s_setprio(0);
  };

  // prologue: A(0), B(0), A(1) in issue order; allow A(1) in flight
  stage(0, 0); stage(0, 1);
  stage(0, 2); stage(0, 3); stage(0, 4); stage(0, 5);
  stage(1, 0); stage(1, 1);
  asm volatile("s_waitcnt vmcnt(2)" ::: "memory");
  __builtin_amdgcn_s_barrier();

  for (int kt = 0; kt < nt; ++kt) {
    const char* bufb = lds[kt & 1];
    // ---- ph0: read A(all) + B(nh0); stage B quarters 0..2 of kt+1 ----
    read_a(bufb);
    read_b(bufb, 0);
    stage(kt + 1, 2); stage(kt + 1, 3); stage(kt + 1, 4);
    __builtin_amdgcn_s_barrier();
    asm volatile("s_waitcnt lgkmcnt(0)" ::: "memory");
    __builtin_amdgcn_sched_barrier(0);
    mfmaq(0);
    __builtin_amdgcn_s_barrier();
    // ---- ph1: read B(nh1); stage B quarter 3 of kt+1, A halves of kt+2 ----
    read_b(bufb, 1);
    stage(kt + 1, 5);
    stage(kt + 2, 0); stage(kt + 2, 1);
    if (kt + 2 < nt)      { asm volatile("s_waitcnt vmcnt(2)" ::: "memory"); }
    else if (kt + 1 < nt) { asm volatile("s_waitcnt vmcnt(0)" ::: "memory"); }
    __builtin_amdgcn_s_barrier();
    asm volatile("s_waitcnt lgkmcnt(0)" ::: "memory");
    __builtin_amdgcn_sched_barrier(0);
    mfmaq(1);
    __builtin_amdgcn_s_barrier();
  }

  // epilogue: C layout col=lane&15, row=(lane>>4)*4+j
#pragma unroll
  for (int ni = 0; ni < 4; ++ni) {
    int col = n0 + wn * 64 + ni * 16 + rl;
    float bv = bias[col];
#pragma unroll
    for (int mi = 0; mi < 4; ++mi) {
      int rbase = m0 + wm * 64 + mi * 16 + cg * 4;
#pragma unroll
      for (int j = 0; j < 4; ++j)
        C[(size_t)(rbase + j) * N + col] = acc[mi][ni][j] + bv;
    }
  }
}

// ---------------- prep: roped Q (scaled 1/sqrt(HD)) and roped new-K ----------------
__global__ __launch_bounds__(256) void prep_qk(const float* __restrict__ mixed,
                                               const float* __restrict__ cost,
                                               const float* __restrict__ sint,
                                               u16* __restrict__ Qb, u16* __restrict__ Kb) {
  int s0 = blockIdx.x * 64, head = blockIdx.y;
  int b = head >> 5, nh = head & 31;
  int tid = threadIdx.x;
  const float qs = 0.08838834764831845f;  // 1/sqrt(128)
#pragma unroll
  for (int i = 0; i < 16; ++i) {
    int flat = i * 256 + tid;    // 4096 = 64 s * 64 j
    int sl = flat >> 6, j = flat & 63;
    int s = s0 + sl;
    size_t base = ((size_t)(s * 2 + b)) * 12288 + (size_t)nh * 384;
    float q1 = mixed[base + j],       q2 = mixed[base + j + 64];
    float k1 = mixed[base + 128 + j], k2 = mixed[base + 192 + j];
    float c = cost[s * 64 + j], sn = sint[s * 64 + j];
    float q1r = q1 * c - q2 * sn, q2r = q2 * c + q1 * sn;
    float k1r = k1 * c - k2 * sn, k2r = k2 * c + k1 * sn;
    size_t qoff = ((size_t)head * SQ + s) * HD;
    Qb[qoff + j]      = f32_to_bf16(q1r * qs);
    Qb[qoff + j + 64] = f32_to_bf16(q2r * qs);
    size_t koff = ((size_t)head * KV + MEML + s) * HD;
    Kb[koff + j]      = f32_to_bf16(k1r);
    Kb[koff + j + 64] = f32_to_bf16(k2r);
  }
}

// ---------------- prep: mem-K copy + V (mem & new) transposed per head ----------------
__global__ __launch_bounds__(256) void prep_kv(const float* __restrict__ mixed,
                                               const float* __restrict__ mem,
                                               u16* __restrict__ Kb, u16* __restrict__ Vtb) {
  int t0 = blockIdx.x * 64, head = blockIdx.y;
  int b = head >> 5, nh = head & 31;
  __shared__ u16 vt[128 * 72];
  int tid = threadIdx.x;
  if (t0 < MEML) {
#pragma unroll
    for (int i = 0; i < 32; ++i) {
      int flat = i * 256 + tid;
      int tl = flat >> 7, d = flat & 127;
      float kvv = mem[((size_t)b * MEML + t0 + tl) * 8192 + (size_t)nh * HD + d];
      Kb[((size_t)head * KV + t0 + tl) * HD + d] = f32_to_bf16(kvv);
    }
  }
#pragma unroll
  for (int i = 0; i < 32; ++i) {
    int flat = i * 256 + tid;
    int tl = flat >> 7, d = flat & 127;
    int t = t0 + tl;
    float v;
    if (t < MEML) v = mem[((size_t)b * MEML + t) * 8192 + 4096 + (size_t)nh * HD + d];
    else          v = mixed[((size_t)((t - MEML) * 2 + b)) * 12288 + (size_t)nh * 384 + 256 + d];
    vt[d * 72 + tl] = f32_to_bf16(v);
  }
  __syncthreads();
#pragma unroll
  for (int i = 0; i < 4; ++i) {
    int c = i * 256 + tid;
    int d = c >> 3, slot = c & 7;
    *(bf16x8*)(Vtb + ((size_t)head * HD + d) * KV + t0 + slot * 8) =
        *(const bf16x8*)(vt + d * 72 + slot * 8);
  }
}

// ---------------- flash attention ----------------
__global__ __launch_bounds__(256) void attn_fwd(const u16* __restrict__ Qb, const u16* __restrict__ Kb,
                                                const u16* __restrict__ Vtb, u16* __restrict__ ctx) {
  __shared__ u16 Ks[64 * 128];
  __shared__ u16 Vts[128 * 64];
  __shared__ u16 Ps[4 * 16 * 64];
  const int tid = threadIdx.x;
  const int lane = tid & 63;
  const int w = tid >> 6;
  const int q0 = blockIdx.x * 64;
  const int head = blockIdx.y;
  const int rl = lane & 15, cg = lane >> 4;

  bf16x8 qf[4];
  {
    const u16* Qrow = Qb + ((size_t)head * SQ + q0 + w * 16 + rl) * HD;
#pragma unroll
    for (int kk = 0; kk < 4; ++kk)
      qf[kk] = *(const bf16x8*)(Qrow + kk * 32 + cg * 8);
  }

  f32x4 acc[8];
#pragma unroll
  for (int i = 0; i < 8; ++i) acc[i] = (f32x4){0.f, 0.f, 0.f, 0.f};
  float mrow[4] = {-3.0e38f, -3.0e38f, -3.0e38f, -3.0e38f};
  float lrow[4] = {0.f, 0.f, 0.f, 0.f};

  const int t_end = q0 + 64 + MEML;

  for (int t0 = 0; t0 < t_end; t0 += 64) {
#pragma unroll
    for (int i = 0; i < 4; ++i) {
      int flat = i * 256 + tid;
      int row = flat >> 4;
      int cb = (flat & 15) << 4;
      int scb = cb ^ ((row & 7) << 4);
      gload_lds16((const char*)(Kb + ((size_t)head * KV + t0 + row) * HD) + scb,
                  (char*)Ks + (flat << 4));
    }
#pragma unroll
    for (int i = 0; i < 4; ++i) {
      int flat = i * 256 + tid;
      int row = flat >> 3;
      int cb = (flat & 7) << 4;
      int scb = cb ^ ((row & 7) << 4);
      gload_lds16((const char*)(Vtb + ((size_t)head * HD + row) * KV + t0) + scb,
                  (char*)Vts + (flat << 4));
    }
    __syncthreads();

    f32x4 sf[4];
#pragma unroll
    for (int tn = 0; tn < 4; ++tn) {
      f32x4 s = (f32x4){0.f, 0.f, 0.f, 0.f};
#pragma unroll
      for (int kk = 0; kk < 4; ++kk) {
        int row = tn * 16 + rl;
        int cb = (kk * 64 + cg * 16) ^ ((row & 7) << 4);
        bf16x8 kf = *(const bf16x8*)((const char*)Ks + row * 256 + cb);
        s = __builtin_amdgcn_mfma_f32_16x16x32_bf16(qf[kk], kf, s, 0, 0, 0);
      }
      sf[tn] = s;
    }
    if (t0 + 63 > MEML + q0 + w * 16) {
#pragma unroll
      for (int tn = 0; tn < 4; ++tn)
#pragma unroll
        for (int j = 0; j < 4; ++j) {
          int t = t0 + tn * 16 + rl;
          int srow = q0 + w * 16 + cg * 4 + j;
          if (t - MEML > srow) sf[tn][j] = -40000.0f;
        }
    }
    float mt[4];
#pragma unroll
    for (int j = 0; j < 4; ++j)
      mt[j] = fmaxf(fmaxf(sf[0][j], sf[1][j]), fmaxf(sf[2][j], sf[3][j]));
#pragma unroll
    for (int off = 1; off <= 8; off <<= 1)
#pragma unroll
      for (int j = 0; j < 4; ++j) mt[j] = fmaxf(mt[j], __shfl_xor(mt[j], off, 64));
    float pscale[4];
#pragma unroll
    for (int j = 0; j < 4; ++j) {
      float mn = fmaxf(mrow[j], mt[j]);
      pscale[j] = __expf(mrow[j] - mn);
      mrow[j] = mn;
    }
    float lsum[4] = {0.f, 0.f, 0.f, 0.f};
#pragma unroll
    for (int tn = 0; tn < 4; ++tn)
#pragma unroll
      for (int j = 0; j < 4; ++j) {
        float p = __expf(sf[tn][j] - mrow[j]);
        lsum[j] += p;
        int prow = cg * 4 + j;
        int colb = (tn * 16 + rl) * 2;
        int addr = w * 2048 + prow * 128 + (colb ^ ((prow & 7) << 4));
        *(u16*)((char*)Ps + addr) = f32_to_bf16(p);
      }
#pragma unroll
    for (int off = 1; off <= 8; off <<= 1)
#pragma unroll
      for (int j = 0; j < 4; ++j) lsum[j] += __shfl_xor(lsum[j], off, 64);
#pragma unroll
    for (int j = 0; j < 4; ++j) lrow[j] = lrow[j] * pscale[j] + lsum[j];
#pragma unroll
    for (int dn = 0; dn < 8; ++dn)
#pragma unroll
      for (int j = 0; j < 4; ++j) acc[dn][j] *= pscale[j];
#pragma unroll
    for (int dn = 0; dn < 8; ++dn) {
#pragma unroll
      for (int kk2 = 0; kk2 < 2; ++kk2) {
        int pcb = (kk2 * 64 + cg * 16) ^ ((rl & 7) << 4);
        bf16x8 pf = *(const bf16x8*)((const char*)Ps + w * 2048 + rl * 128 + pcb);
        int vrow = dn * 16 + rl;
        int vcb = (kk2 * 64 + cg * 16) ^ ((vrow & 7) << 4);
        bf16x8 vf = *(const bf16x8*)((const char*)Vts + vrow * 128 + vcb);
        acc[dn] = __builtin_amdgcn_mfma_f32_16x16x32_bf16(pf, vf, acc[dn], 0, 0, 0);
      }
    }
    __syncthreads();
  }
  const int b = head >> 5, nh = head & 31;
#pragma unroll
  for (int dn = 0; dn < 8; ++dn)
#pragma unroll
    for (int j = 0; j < 4; ++j) {
      int srow = q0 + w * 16 + cg * 4 + j;
      float v = acc[dn][j] / lrow[j];
      ctx[((size_t)(srow * 2 + b)) * H + (size_t)nh * HD + dn * 16 + rl] = f32_to_bf16(v);
    }
}

// ---------------- launch ----------------
extern "C" void kernel_launch(void* const* d_in, const int* in_sizes, int n_in,
                              void* d_out, int out_size, void* d_ws, size_t ws_size,
                              hipStream_t stream) {
  const float* hidden  = (const float*)d_in[0];
  const float* mem     = (const float*)d_in[3];
  const float* qkv_w   = (const float*)d_in[4];
  const float* qkv_b   = (const float*)d_in[5];
  const float* dense_w = (const float*)d_in[6];
  const float* dense_b = (const float*)d_in[7];
  float* out = (float*)d_out;
  char* ws = (char*)d_ws;

  float* mixed = (float*)ws;                      // 100,663,296 B (2048x12288 f32)
  char* R1 = ws + 100663296;
  u16* hid_bf = (u16*)R1;                         // aliased: pre-GEMM1 use
  u16* qw_bf  = (u16*)(R1 + 16777216);
  u16* Qb  = (u16*)R1;
  u16* Kb  = (u16*)(R1 + 16777216);
  u16* Vtb = (u16*)(R1 + 50331648);
  u16* ctx = (u16*)(R1 + 83886080);
  u16* dw_bf = (u16*)(R1 + 100663296);
  float* cost = (float*)(ws + 234881024);
  float* sint = (float*)(ws + 234881024 + 262144);

  conv_bf16<<<8192, 256, 0, stream>>>(hidden, hid_bf, 2097152);
  conv_bf16<<<49152, 256, 0, stream>>>(qkv_w, qw_bf, 12582912);
  rope_tables<<<256, 256, 0, stream>>>(cost, sint);
  gemm8<<<dim3(48, 16), 512, 0, stream>>>(hid_bf, qw_bf, qkv_b, mixed, 12288, 4096);
  prep_qk<<<dim3(16, 64), 256, 0, stream>>>(mixed, cost, sint, Qb, Kb);
  prep_kv<<<dim3(32, 64), 256, 0, stream>>>(mixed, mem, Kb, Vtb);
  conv_bf16<<<16384, 256, 0, stream>>>(dense_w, dw_bf, 4194304);
  attn_fwd<<<dim3(16, 64), 256, 0, stream>>>(Qb, Kb, Vtb, ctx);
  gemm8<<<dim3(16, 16), 512, 0, stream>>>(ctx, dw_bf, dense_b, out, 4096, 4096);
}

// Round 4
// 623.894 us; speedup vs baseline: 1.0331x; 1.0147x over previous
//
#include <hip/hip_runtime.h>

// SelfAttention (Transformer-XL style) on gfx950.
// convert->bf16, GEMM1 (256x256 m201-port, bf16 out), RoPE prep, flash attn, GEMM2.

typedef __attribute__((ext_vector_type(4))) float f32x4;
typedef __attribute__((ext_vector_type(8))) short bf16x8;
typedef unsigned short u16;

#define SQ   1024
#define BSZ  2
#define H    4096
#define NH   32
#define HD   128
#define MEML 1024
#define KV   2048

__device__ __forceinline__ u16 f32_to_bf16(float f) {
  union { float f; unsigned int u; } v; v.f = f;
  unsigned int r = v.u + 0x7FFFu + ((v.u >> 16) & 1u);
  return (u16)(r >> 16);
}
__device__ __forceinline__ float bf16_to_f32(u16 x) {
  union { unsigned int u; float f; } v; v.u = ((unsigned int)x) << 16; return v.f;
}

__device__ __forceinline__ void gload_lds16(const void* g, void* l) {
  __builtin_amdgcn_global_load_lds((const __attribute__((address_space(1))) void*)g,
                                   (__attribute__((address_space(3))) void*)l, 16, 0, 0);
}

// ---------------- f32 -> bf16 convert ----------------
__global__ __launch_bounds__(256) void conv_bf16(const float* __restrict__ in,
                                                 u16* __restrict__ out, int n4) {
  int idx = blockIdx.x * 256 + threadIdx.x;
  if (idx < n4) {
    float4 v = ((const float4*)in)[idx];
    ushort4 o;
    o.x = f32_to_bf16(v.x); o.y = f32_to_bf16(v.y);
    o.z = f32_to_bf16(v.z); o.w = f32_to_bf16(v.w);
    ((ushort4*)out)[idx] = o;
  }
}

// ---------------- RoPE tables ----------------
__global__ __launch_bounds__(256) void rope_tables(float* __restrict__ cost, float* __restrict__ sint) {
  int idx = blockIdx.x * 256 + threadIdx.x;   // 65536 = 1024 s * 64 j
  int s = idx >> 6, j = idx & 63;
  float inv = powf(10000.0f, -(float)j / 64.0f);
  float ang = (float)(MEML + s) * inv;
  cost[idx] = cosf(ang);
  sint[idx] = sinf(ang);
}

// ---------------- 256x256 GEMM (m201 geometry): C = A * B^T + bias ----------------
// BK=64; 512 threads = 8 waves (2M x 4N), per-wave 128x64 out, acc[8][4].
// LDS 128 KiB: 2 bufs x regions {A0,A1,B0,B1} of 16 KiB (128 rows x 128 B).
// 4 phases/K-tile, 16 MFMA each; 1 half-stage per phase; vmcnt(4) once per tile.
template <typename OUT_T>
__global__ __launch_bounds__(512, 2) void gemm256(const u16* __restrict__ A, const u16* __restrict__ B,
                                                  const float* __restrict__ bias, OUT_T* __restrict__ C,
                                                  int N, int K) {
  __shared__ char lds[2][65536];
  const int tid = threadIdx.x;
  const int lane = tid & 63;
  const int w = tid >> 6;
  const int wm = w >> 2, wn = w & 3;
  const int rl = lane & 15, cg = lane >> 4;
  const int m0 = blockIdx.y * 256, n0 = blockIdx.x * 256;
  const int nt = K >> 6;

  // stage half r of K-tile `tile`: r 0/1 = A rows r*128.., r 2/3 = B rows (r-2)*128..
  auto stage = [&](int tile, int r) {
    if (tile >= nt) return;
    char* dstbase = lds[tile & 1] + r * 16384;
    const u16* srcb = (r < 2) ? (A + (size_t)(m0 + r * 128) * K)
                              : (B + (size_t)(n0 + (r - 2) * 128) * K);
#pragma unroll
    for (int q = 0; q < 2; ++q) {
      int flat = q * 512 + tid;
      int row = flat >> 3;
      int scb = ((flat & 7) << 4) ^ ((row & 7) << 4);   // pre-swizzled source col
      gload_lds16((const char*)(srcb + (size_t)row * K + (size_t)tile * 64) + scb,
                  dstbase + flat * 16);
    }
  };

  f32x4 acc[8][4];
#pragma unroll
  for (int i = 0; i < 8; ++i)
#pragma unroll
    for (int j = 0; j < 4; ++j) acc[i][j] = (f32x4){0.f, 0.f, 0.f, 0.f};

  bf16x8 af[4][2], bf0[2][2], bf1[2][2];

  auto read_a = [&](const char* buf, int mh) {
#pragma unroll
    for (int mi = 0; mi < 4; ++mi) {
      int lr = mh * 64 + mi * 16 + rl;            // region-local row
#pragma unroll
      for (int kk = 0; kk < 2; ++kk) {
        int cb = (kk * 64 + cg * 16) ^ ((lr & 7) << 4);
        af[mi][kk] = *(const bf16x8*)(buf + wm * 16384 + lr * 128 + cb);
      }
    }
  };
  auto read_b = [&](const char* buf, int nh, bf16x8 (&bb)[2][2]) {
#pragma unroll
    for (int nl = 0; nl < 2; ++nl) {
      int lr = (wn & 1) * 64 + (nh * 2 + nl) * 16 + rl;
#pragma unroll
      for (int kk = 0; kk < 2; ++kk) {
        int cb = (kk * 64 + cg * 16) ^ ((lr & 7) << 4);
        bb[nl][kk] = *(const bf16x8*)(buf + 32768 + (wn >> 1) * 16384 + lr * 128 + cb);
      }
    }
  };
  auto mfmaq = [&](int mh, int nh, bf16x8 (&bb)[2][2]) {
    __builtin_amdgcn_s_setprio(1);
#pragma unroll
    for (int kk = 0; kk < 2; ++kk)
#pragma unroll
      for (int mi = 0; mi < 4; ++mi)
#pragma unroll
        for (int nl = 0; nl < 2; ++nl)
          acc[mh * 4 + mi][nh * 2 + nl] = __builtin_amdgcn_mfma_f32_16x16x32_bf16(
              af[mi][kk], bb[nl][kk], acc[mh * 4 + mi][nh * 2 + nl], 0, 0, 0);
    __builtin_amdgcn_s_setprio(0);
  };

  // prologue: queue = [0.B0, 0.B1, 0.A0, 0.A1, 1.B0, 1.B1]; wait tile0 landed
  stage(0, 2); stage(0, 3); stage(0, 0); stage(0, 1);
  stage(1, 2); stage(1, 3);
  asm volatile("s_waitcnt vmcnt(4)" ::: "memory");
  __builtin_amdgcn_s_barrier();

  for (int kt = 0; kt < nt; ++kt) {
    const char* buf = lds[kt & 1];
    // ph0: quadrant (0,0); stage (kt+1).A0 -> p^1
    read_a(buf, 0);
    read_b(buf, 0, bf0);
    stage(kt + 1, 0);
    __builtin_amdgcn_s_barrier();
    asm volatile("s_waitcnt lgkmcnt(0)" ::: "memory");
    mfmaq(0, 0, bf0);
    __builtin_amdgcn_s_barrier();
    // ph1: quadrant (0,1); stage (kt+1).A1 -> p^1
    read_b(buf, 1, bf1);
    stage(kt + 1, 1);
    __builtin_amdgcn_s_barrier();
    asm volatile("s_waitcnt lgkmcnt(0)" ::: "memory");
    mfmaq(0, 1, bf1);
    __builtin_amdgcn_s_barrier();
    // ph2: quadrant (1,1); stage (kt+2).B0 -> p (B regions of p free after ph1)
    read_a(buf, 1);
    stage(kt + 2, 2);
    __builtin_amdgcn_s_barrier();
    asm volatile("s_waitcnt lgkmcnt(0)" ::: "memory");
    mfmaq(1, 1, bf1);
    __builtin_amdgcn_s_barrier();
    // ph3: quadrant (1,0); stage (kt+2).B1 -> p; counted vmcnt AFTER mfma
    stage(kt + 2, 3);
    __builtin_amdgcn_s_barrier();
    mfmaq(1, 0, bf0);
    if (kt + 2 < nt)      { asm volatile("s_waitcnt vmcnt(4)" ::: "memory"); }
    else if (kt + 1 < nt) { asm volatile("s_waitcnt vmcnt(0)" ::: "memory"); }
    __builtin_amdgcn_s_barrier();
  }

  // epilogue: C layout col=lane&15, row=(lane>>4)*4+j
#pragma unroll
  for (int ni = 0; ni < 4; ++ni) {
    int col = n0 + wn * 64 + ni * 16 + rl;
    float bv = bias[col];
#pragma unroll
    for (int mi = 0; mi < 8; ++mi) {
      int rbase = m0 + wm * 128 + mi * 16 + cg * 4;
#pragma unroll
      for (int j = 0; j < 4; ++j) {
        float v = acc[mi][ni][j] + bv;
        if constexpr (sizeof(OUT_T) == 2)
          C[(size_t)(rbase + j) * N + col] = (OUT_T)f32_to_bf16(v);
        else
          C[(size_t)(rbase + j) * N + col] = (OUT_T)v;
      }
    }
  }
}

// ---------------- prep: roped Q (scaled) and roped new-K (mixed is bf16 now) ----------
__global__ __launch_bounds__(256) void prep_qk(const u16* __restrict__ mixed,
                                               const float* __restrict__ cost,
                                               const float* __restrict__ sint,
                                               u16* __restrict__ Qb, u16* __restrict__ Kb) {
  int s0 = blockIdx.x * 64, head = blockIdx.y;
  int b = head >> 5, nh = head & 31;
  int tid = threadIdx.x;
  const float qs = 0.08838834764831845f;  // 1/sqrt(128)
#pragma unroll
  for (int i = 0; i < 16; ++i) {
    int flat = i * 256 + tid;    // 4096 = 64 s * 64 j
    int sl = flat >> 6, j = flat & 63;
    int s = s0 + sl;
    size_t base = ((size_t)(s * 2 + b)) * 12288 + (size_t)nh * 384;
    float q1 = bf16_to_f32(mixed[base + j]),       q2 = bf16_to_f32(mixed[base + j + 64]);
    float k1 = bf16_to_f32(mixed[base + 128 + j]), k2 = bf16_to_f32(mixed[base + 192 + j]);
    float c = cost[s * 64 + j], sn = sint[s * 64 + j];
    float q1r = q1 * c - q2 * sn, q2r = q2 * c + q1 * sn;
    float k1r = k1 * c - k2 * sn, k2r = k2 * c + k1 * sn;
    size_t qoff = ((size_t)head * SQ + s) * HD;
    Qb[qoff + j]      = f32_to_bf16(q1r * qs);
    Qb[qoff + j + 64] = f32_to_bf16(q2r * qs);
    size_t koff = ((size_t)head * KV + MEML + s) * HD;
    Kb[koff + j]      = f32_to_bf16(k1r);
    Kb[koff + j + 64] = f32_to_bf16(k2r);
  }
}

// ---------------- prep: mem-K copy + V transposed per head ----------------
__global__ __launch_bounds__(256) void prep_kv(const u16* __restrict__ mixed,
                                               const float* __restrict__ mem,
                                               u16* __restrict__ Kb, u16* __restrict__ Vtb) {
  int t0 = blockIdx.x * 64, head = blockIdx.y;
  int b = head >> 5, nh = head & 31;
  __shared__ u16 vt[128 * 72];
  int tid = threadIdx.x;
  if (t0 < MEML) {
#pragma unroll
    for (int i = 0; i < 32; ++i) {
      int flat = i * 256 + tid;
      int tl = flat >> 7, d = flat & 127;
      float kvv = mem[((size_t)b * MEML + t0 + tl) * 8192 + (size_t)nh * HD + d];
      Kb[((size_t)head * KV + t0 + tl) * HD + d] = f32_to_bf16(kvv);
    }
  }
#pragma unroll
  for (int i = 0; i < 32; ++i) {
    int flat = i * 256 + tid;
    int tl = flat >> 7, d = flat & 127;
    int t = t0 + tl;
    u16 v;
    if (t < MEML) v = f32_to_bf16(mem[((size_t)b * MEML + t) * 8192 + 4096 + (size_t)nh * HD + d]);
    else          v = mixed[((size_t)((t - MEML) * 2 + b)) * 12288 + (size_t)nh * 384 + 256 + d];
    vt[d * 72 + tl] = v;
  }
  __syncthreads();
#pragma unroll
  for (int i = 0; i < 4; ++i) {
    int c = i * 256 + tid;
    int d = c >> 3, slot = c & 7;
    *(bf16x8*)(Vtb + ((size_t)head * HD + d) * KV + t0 + slot * 8) =
        *(const bf16x8*)(vt + d * 72 + slot * 8);
  }
}

// ---------------- flash attention ----------------
__global__ __launch_bounds__(256) void attn_fwd(const u16* __restrict__ Qb, const u16* __restrict__ Kb,
                                                const u16* __restrict__ Vtb, u16* __restrict__ ctx) {
  __shared__ u16 Ks[64 * 128];
  __shared__ u16 Vts[128 * 64];
  __shared__ u16 Ps[4 * 16 * 64];
  const int tid = threadIdx.x;
  const int lane = tid & 63;
  const int w = tid >> 6;
  const int q0 = blockIdx.x * 64;
  const int head = blockIdx.y;
  const int rl = lane & 15, cg = lane >> 4;

  bf16x8 qf[4];
  {
    const u16* Qrow = Qb + ((size_t)head * SQ + q0 + w * 16 + rl) * HD;
#pragma unroll
    for (int kk = 0; kk < 4; ++kk)
      qf[kk] = *(const bf16x8*)(Qrow + kk * 32 + cg * 8);
  }

  f32x4 acc[8];
#pragma unroll
  for (int i = 0; i < 8; ++i) acc[i] = (f32x4){0.f, 0.f, 0.f, 0.f};
  float mrow[4] = {-3.0e38f, -3.0e38f, -3.0e38f, -3.0e38f};
  float lrow[4] = {0.f, 0.f, 0.f, 0.f};

  const int t_end = q0 + 64 + MEML;

  for (int t0 = 0; t0 < t_end; t0 += 64) {
#pragma unroll
    for (int i = 0; i < 4; ++i) {
      int flat = i * 256 + tid;
      int row = flat >> 4;
      int cb = (flat & 15) << 4;
      int scb = cb ^ ((row & 7) << 4);
      gload_lds16((const char*)(Kb + ((size_t)head * KV + t0 + row) * HD) + scb,
                  (char*)Ks + (flat << 4));
    }
#pragma unroll
    for (int i = 0; i < 4; ++i) {
      int flat = i * 256 + tid;
      int row = flat >> 3;
      int cb = (flat & 7) << 4;
      int scb = cb ^ ((row & 7) << 4);
      gload_lds16((const char*)(Vtb + ((size_t)head * HD + row) * KV + t0) + scb,
                  (char*)Vts + (flat << 4));
    }
    __syncthreads();

    f32x4 sf[4];
#pragma unroll
    for (int tn = 0; tn < 4; ++tn) {
      f32x4 s = (f32x4){0.f, 0.f, 0.f, 0.f};
#pragma unroll
      for (int kk = 0; kk < 4; ++kk) {
        int row = tn * 16 + rl;
        int cb = (kk * 64 + cg * 16) ^ ((row & 7) << 4);
        bf16x8 kf = *(const bf16x8*)((const char*)Ks + row * 256 + cb);
        s = __builtin_amdgcn_mfma_f32_16x16x32_bf16(qf[kk], kf, s, 0, 0, 0);
      }
      sf[tn] = s;
    }
    if (t0 + 63 > MEML + q0 + w * 16) {
#pragma unroll
      for (int tn = 0; tn < 4; ++tn)
#pragma unroll
        for (int j = 0; j < 4; ++j) {
          int t = t0 + tn * 16 + rl;
          int srow = q0 + w * 16 + cg * 4 + j;
          if (t - MEML > srow) sf[tn][j] = -40000.0f;
        }
    }
    float mt[4];
#pragma unroll
    for (int j = 0; j < 4; ++j)
      mt[j] = fmaxf(fmaxf(sf[0][j], sf[1][j]), fmaxf(sf[2][j], sf[3][j]));
#pragma unroll
    for (int off = 1; off <= 8; off <<= 1)
#pragma unroll
      for (int j = 0; j < 4; ++j) mt[j] = fmaxf(mt[j], __shfl_xor(mt[j], off, 64));
    float pscale[4];
#pragma unroll
    for (int j = 0; j < 4; ++j) {
      float mn = fmaxf(mrow[j], mt[j]);
      pscale[j] = __expf(mrow[j] - mn);
      mrow[j] = mn;
    }
    float lsum[4] = {0.f, 0.f, 0.f, 0.f};
#pragma unroll
    for (int tn = 0; tn < 4; ++tn)
#pragma unroll
      for (int j = 0; j < 4; ++j) {
        float p = __expf(sf[tn][j] - mrow[j]);
        lsum[j] += p;
        int prow = cg * 4 + j;
        int colb = (tn * 16 + rl) * 2;
        int addr = w * 2048 + prow * 128 + (colb ^ ((prow & 7) << 4));
        *(u16*)((char*)Ps + addr) = f32_to_bf16(p);
      }
#pragma unroll
    for (int off = 1; off <= 8; off <<= 1)
#pragma unroll
      for (int j = 0; j < 4; ++j) lsum[j] += __shfl_xor(lsum[j], off, 64);
#pragma unroll
    for (int j = 0; j < 4; ++j) lrow[j] = lrow[j] * pscale[j] + lsum[j];
#pragma unroll
    for (int dn = 0; dn < 8; ++dn)
#pragma unroll
      for (int j = 0; j < 4; ++j) acc[dn][j] *= pscale[j];
#pragma unroll
    for (int dn = 0; dn < 8; ++dn) {
#pragma unroll
      for (int kk2 = 0; kk2 < 2; ++kk2) {
        int pcb = (kk2 * 64 + cg * 16) ^ ((rl & 7) << 4);
        bf16x8 pf = *(const bf16x8*)((const char*)Ps + w * 2048 + rl * 128 + pcb);
        int vrow = dn * 16 + rl;
        int vcb = (kk2 * 64 + cg * 16) ^ ((vrow & 7) << 4);
        bf16x8 vf = *(const bf16x8*)((const char*)Vts + vrow * 128 + vcb);
        acc[dn] = __builtin_amdgcn_mfma_f32_16x16x32_bf16(pf, vf, acc[dn], 0, 0, 0);
      }
    }
    __syncthreads();
  }
  const int b = head >> 5, nh = head & 31;
#pragma unroll
  for (int dn = 0; dn < 8; ++dn)
#pragma unroll
    for (int j = 0; j < 4; ++j) {
      int srow = q0 + w * 16 + cg * 4 + j;
      float v = acc[dn][j] / lrow[j];
      ctx[((size_t)(srow * 2 + b)) * H + (size_t)nh * HD + dn * 16 + rl] = f32_to_bf16(v);
    }
}

// ---------------- launch ----------------
extern "C" void kernel_launch(void* const* d_in, const int* in_sizes, int n_in,
                              void* d_out, int out_size, void* d_ws, size_t ws_size,
                              hipStream_t stream) {
  const float* hidden  = (const float*)d_in[0];
  const float* mem     = (const float*)d_in[3];
  const float* qkv_w   = (const float*)d_in[4];
  const float* qkv_b   = (const float*)d_in[5];
  const float* dense_w = (const float*)d_in[6];
  const float* dense_b = (const float*)d_in[7];
  float* out = (float*)d_out;
  char* ws = (char*)d_ws;

  u16* mixed = (u16*)ws;                          // 50,331,648 B used (2048x12288 bf16)
  char* R1 = ws + 100663296;
  u16* hid_bf = (u16*)R1;                         // aliased: pre-GEMM1 use
  u16* qw_bf  = (u16*)(R1 + 16777216);
  u16* Qb  = (u16*)R1;
  u16* Kb  = (u16*)(R1 + 16777216);
  u16* Vtb = (u16*)(R1 + 50331648);
  u16* ctx = (u16*)(R1 + 83886080);
  u16* dw_bf = (u16*)(R1 + 100663296);
  float* cost = (float*)(ws + 234881024);
  float* sint = (float*)(ws + 234881024 + 262144);

  conv_bf16<<<8192, 256, 0, stream>>>(hidden, hid_bf, 2097152);
  conv_bf16<<<49152, 256, 0, stream>>>(qkv_w, qw_bf, 12582912);
  rope_tables<<<256, 256, 0, stream>>>(cost, sint);
  gemm256<u16><<<dim3(48, 8), 512, 0, stream>>>(hid_bf, qw_bf, qkv_b, mixed, 12288, 4096);
  prep_qk<<<dim3(16, 64), 256, 0, stream>>>(mixed, cost, sint, Qb, Kb);
  prep_kv<<<dim3(32, 64), 256, 0, stream>>>(mixed, mem, Kb, Vtb);
  conv_bf16<<<16384, 256, 0, stream>>>(dense_w, dw_bf, 4194304);
  attn_fwd<<<dim3(16, 64), 256, 0, stream>>>(Qb, Kb, Vtb, ctx);
  gemm256<float><<<dim3(16, 8), 512, 0, stream>>>(ctx, dw_bf, dense_b, out, 4096, 4096);
}

// Round 5
// 562.319 us; speedup vs baseline: 1.1462x; 1.1095x over previous
//
#include <hip/hip_runtime.h>

// SelfAttention (Transformer-XL style) on gfx950.
// convert->bf16, GEMM1 (256x192 tiles, 2 exact rounds), RoPE prep, flash attn,
// GEMM2 (256x128 tiles, 1 exact round). bf16 MFMA 16x16x32, f32 accumulate.

typedef __attribute__((ext_vector_type(4))) float f32x4;
typedef __attribute__((ext_vector_type(8))) short bf16x8;
typedef unsigned short u16;

#define SQ   1024
#define BSZ  2
#define H    4096
#define NH   32
#define HD   128
#define MEML 1024
#define KV   2048

__device__ __forceinline__ u16 f32_to_bf16(float f) {
  union { float f; unsigned int u; } v; v.f = f;
  unsigned int r = v.u + 0x7FFFu + ((v.u >> 16) & 1u);
  return (u16)(r >> 16);
}
__device__ __forceinline__ float bf16_to_f32(u16 x) {
  union { unsigned int u; float f; } v; v.u = ((unsigned int)x) << 16; return v.f;
}

__device__ __forceinline__ void gload_lds16(const void* g, void* l) {
  __builtin_amdgcn_global_load_lds((const __attribute__((address_space(1))) void*)g,
                                   (__attribute__((address_space(3))) void*)l, 16, 0, 0);
}

// ---------------- f32 -> bf16 convert ----------------
__global__ __launch_bounds__(256) void conv_bf16(const float* __restrict__ in,
                                                 u16* __restrict__ out, int n4) {
  int idx = blockIdx.x * 256 + threadIdx.x;
  if (idx < n4) {
    float4 v = ((const float4*)in)[idx];
    ushort4 o;
    o.x = f32_to_bf16(v.x); o.y = f32_to_bf16(v.y);
    o.z = f32_to_bf16(v.z); o.w = f32_to_bf16(v.w);
    ((ushort4*)out)[idx] = o;
  }
}

// ---------------- RoPE tables ----------------
__global__ __launch_bounds__(256) void rope_tables(float* __restrict__ cost, float* __restrict__ sint) {
  int idx = blockIdx.x * 256 + threadIdx.x;   // 65536 = 1024 s * 64 j
  int s = idx >> 6, j = idx & 63;
  float inv = powf(10000.0f, -(float)j / 64.0f);
  float ang = (float)(MEML + s) * inv;
  cost[idx] = cosf(ang);
  sint[idx] = sinf(ang);
}

// ---------------- GEMM: C[M,N] = A[M,K](bf16) * B[N,K]^T(bf16) + bias[N] ----------
// BM=256, BN=NF*64, BK=64; 512 threads = 8 waves (2M x 4N), per-wave 128 x NF*16.
// 4 phases/K-tile (round-4 schedule); 8KiB stage units; vmcnt(NF) once per tile.
template <typename OUT_T, int NF>
__global__ __launch_bounds__(512, 2) void gemmT(const u16* __restrict__ A, const u16* __restrict__ B,
                                                const float* __restrict__ bias, OUT_T* __restrict__ C,
                                                int N, int K) {
  constexpr int WN = NF * 16;                 // per-wave N width
  constexpr int NH0 = (NF + 1) / 2;           // frags in set0
  constexpr int SB2 = NF - (NF >> 1);         // B units staged at ph2
  __shared__ char lds[2][32768 + NF * 8192];  // A rows 0..255 @0, B rows @32768 (linear r*128)
  const int tid = threadIdx.x;
  const int lane = tid & 63;
  const int w = tid >> 6;
  const int wm = w >> 2, wn = w & 3;
  const int rl = lane & 15, cg = lane >> 4;
  const int m0 = blockIdx.y * 256, n0 = blockIdx.x * (NF * 64);
  const int nt = K >> 6;

  const int srow = tid >> 3;                              // 0..63 (unit-local row)
  const int scb = ((tid & 7) << 4) ^ ((srow & 7) << 4);   // pre-swizzled source byte col

  auto stage_a = [&](int tile, int ua) {
    if (tile >= nt) return;
    gload_lds16((const char*)(A + (size_t)(m0 + ua * 64 + srow) * K + (size_t)tile * 64) + scb,
                lds[tile & 1] + ua * 8192 + tid * 16);
  };
  auto stage_b = [&](int tile, int ub) {
    if (tile >= nt) return;
    gload_lds16((const char*)(B + (size_t)(n0 + ub * 64 + srow) * K + (size_t)tile * 64) + scb,
                lds[tile & 1] + 32768 + ub * 8192 + tid * 16);
  };

  f32x4 acc[8][NF];
#pragma unroll
  for (int i = 0; i < 8; ++i)
#pragma unroll
    for (int j = 0; j < NF; ++j) acc[i][j] = (f32x4){0.f, 0.f, 0.f, 0.f};

  bf16x8 af[4][2], bf[NF][2];

  auto read_a = [&](const char* buf, int mh) {
#pragma unroll
    for (int mi = 0; mi < 4; ++mi) {
      int R = wm * 128 + mh * 64 + mi * 16 + rl;
#pragma unroll
      for (int kk = 0; kk < 2; ++kk) {
        int cb = (kk * 64 + cg * 16) ^ ((R & 7) << 4);
        af[mi][kk] = *(const bf16x8*)(buf + R * 128 + cb);
      }
    }
  };
  auto read_b1 = [&](const char* buf, int nl) {
    int R = wn * WN + nl * 16 + rl;
#pragma unroll
    for (int kk = 0; kk < 2; ++kk) {
      int cb = (kk * 64 + cg * 16) ^ ((R & 7) << 4);
      bf[nl][kk] = *(const bf16x8*)(buf + 32768 + R * 128 + cb);
    }
  };
  auto mfset = [&](int mh, int lo, int hi) {
    __builtin_amdgcn_s_setprio(1);
#pragma unroll
    for (int kk = 0; kk < 2; ++kk)
#pragma unroll
      for (int mi = 0; mi < 4; ++mi)
#pragma unroll
        for (int nl = 0; nl < NF; ++nl)
          if (nl >= lo && nl < hi)
            acc[mh * 4 + mi][nl] = __builtin_amdgcn_mfma_f32_16x16x32_bf16(
                af[mi][kk], bf[nl][kk], acc[mh * 4 + mi][nl], 0, 0, 0);
    __builtin_amdgcn_s_setprio(0);
  };

  // prologue: tile0 A+B, tile1 B; wait tile0 landed (tile1.B = NF outstanding)
#pragma unroll
  for (int ua = 0; ua < 4; ++ua) stage_a(0, ua);
#pragma unroll
  for (int ub = 0; ub < NF; ++ub) stage_b(0, ub);
#pragma unroll
  for (int ub = 0; ub < NF; ++ub) stage_b(1, ub);
  if (NF == 2)      { asm volatile("s_waitcnt vmcnt(2)" ::: "memory"); }
  else if (NF == 3) { asm volatile("s_waitcnt vmcnt(3)" ::: "memory"); }
  else              { asm volatile("s_waitcnt vmcnt(4)" ::: "memory"); }
  __builtin_amdgcn_s_barrier();

  for (int kt = 0; kt < nt; ++kt) {
    const char* buf = lds[kt & 1];
    // ph0: quadrant (mh0,set0); stage (kt+1).A units 0,1 -> p^1
    read_a(buf, 0);
#pragma unroll
    for (int nl = 0; nl < NH0; ++nl) read_b1(buf, nl);
    stage_a(kt + 1, 0); stage_a(kt + 1, 1);
    __builtin_amdgcn_s_barrier();
    asm volatile("s_waitcnt lgkmcnt(0)" ::: "memory");
    mfset(0, 0, NH0);
    __builtin_amdgcn_s_barrier();
    // ph1: quadrant (mh0,set1); stage (kt+1).A units 2,3 -> p^1
#pragma unroll
    for (int nl = NH0; nl < NF; ++nl) read_b1(buf, nl);
    stage_a(kt + 1, 2); stage_a(kt + 1, 3);
    __builtin_amdgcn_s_barrier();
    asm volatile("s_waitcnt lgkmcnt(0)" ::: "memory");
    mfset(0, NH0, NF);
    __builtin_amdgcn_s_barrier();
    // ph2: quadrant (mh1,set1); stage (kt+2).B units 0..SB2-1 -> p (B of p free after ph1)
    read_a(buf, 1);
#pragma unroll
    for (int ub = 0; ub < SB2; ++ub) stage_b(kt + 2, ub);
    __builtin_amdgcn_s_barrier();
    asm volatile("s_waitcnt lgkmcnt(0)" ::: "memory");
    mfset(1, NH0, NF);
    __builtin_amdgcn_s_barrier();
    // ph3: quadrant (mh1,set0); stage (kt+2).B units SB2..NF-1 -> p; counted vmcnt
#pragma unroll
    for (int ub = SB2; ub < NF; ++ub) stage_b(kt + 2, ub);
    __builtin_amdgcn_s_barrier();
    mfset(1, 0, NH0);
    if (kt + 2 < nt) {
      if (NF == 2)      { asm volatile("s_waitcnt vmcnt(2)" ::: "memory"); }
      else if (NF == 3) { asm volatile("s_waitcnt vmcnt(3)" ::: "memory"); }
      else              { asm volatile("s_waitcnt vmcnt(4)" ::: "memory"); }
    } else if (kt + 1 < nt) {
      asm volatile("s_waitcnt vmcnt(0)" ::: "memory");
    }
    __builtin_amdgcn_s_barrier();
  }

  // epilogue: C layout col=lane&15, row=(lane>>4)*4+j ; acc row r <-> M offset 16*r
#pragma unroll
  for (int ni = 0; ni < NF; ++ni) {
    int col = n0 + wn * WN + ni * 16 + rl;
    float bv = bias[col];
#pragma unroll
    for (int mi = 0; mi < 8; ++mi) {
      int rbase = m0 + wm * 128 + mi * 16 + cg * 4;
#pragma unroll
      for (int j = 0; j < 4; ++j) {
        float v = acc[mi][ni][j] + bv;
        if constexpr (sizeof(OUT_T) == 2)
          C[(size_t)(rbase + j) * N + col] = (OUT_T)f32_to_bf16(v);
        else
          C[(size_t)(rbase + j) * N + col] = (OUT_T)v;
      }
    }
  }
}

// ---------------- prep: roped Q (scaled) and roped new-K (mixed is bf16) ----------
__global__ __launch_bounds__(256) void prep_qk(const u16* __restrict__ mixed,
                                               const float* __restrict__ cost,
                                               const float* __restrict__ sint,
                                               u16* __restrict__ Qb, u16* __restrict__ Kb) {
  int s0 = blockIdx.x * 64, head = blockIdx.y;
  int b = head >> 5, nh = head & 31;
  int tid = threadIdx.x;
  const float qs = 0.08838834764831845f;  // 1/sqrt(128)
#pragma unroll
  for (int i = 0; i < 16; ++i) {
    int flat = i * 256 + tid;    // 4096 = 64 s * 64 j
    int sl = flat >> 6, j = flat & 63;
    int s = s0 + sl;
    size_t base = ((size_t)(s * 2 + b)) * 12288 + (size_t)nh * 384;
    float q1 = bf16_to_f32(mixed[base + j]),       q2 = bf16_to_f32(mixed[base + j + 64]);
    float k1 = bf16_to_f32(mixed[base + 128 + j]), k2 = bf16_to_f32(mixed[base + 192 + j]);
    float c = cost[s * 64 + j], sn = sint[s * 64 + j];
    float q1r = q1 * c - q2 * sn, q2r = q2 * c + q1 * sn;
    float k1r = k1 * c - k2 * sn, k2r = k2 * c + k1 * sn;
    size_t qoff = ((size_t)head * SQ + s) * HD;
    Qb[qoff + j]      = f32_to_bf16(q1r * qs);
    Qb[qoff + j + 64] = f32_to_bf16(q2r * qs);
    size_t koff = ((size_t)head * KV + MEML + s) * HD;
    Kb[koff + j]      = f32_to_bf16(k1r);
    Kb[koff + j + 64] = f32_to_bf16(k2r);
  }
}

// ---------------- prep: mem-K copy + V transposed per head ----------------
__global__ __launch_bounds__(256) void prep_kv(const u16* __restrict__ mixed,
                                               const float* __restrict__ mem,
                                               u16* __restrict__ Kb, u16* __restrict__ Vtb) {
  int t0 = blockIdx.x * 64, head = blockIdx.y;
  int b = head >> 5, nh = head & 31;
  __shared__ u16 vt[128 * 72];
  int tid = threadIdx.x;
  if (t0 < MEML) {
#pragma unroll
    for (int i = 0; i < 32; ++i) {
      int flat = i * 256 + tid;
      int tl = flat >> 7, d = flat & 127;
      float kvv = mem[((size_t)b * MEML + t0 + tl) * 8192 + (size_t)nh * HD + d];
      Kb[((size_t)head * KV + t0 + tl) * HD + d] = f32_to_bf16(kvv);
    }
  }
#pragma unroll
  for (int i = 0; i < 32; ++i) {
    int flat = i * 256 + tid;
    int tl = flat >> 7, d = flat & 127;
    int t = t0 + tl;
    u16 v;
    if (t < MEML) v = f32_to_bf16(mem[((size_t)b * MEML + t) * 8192 + 4096 + (size_t)nh * HD + d]);
    else          v = mixed[((size_t)((t - MEML) * 2 + b)) * 12288 + (size_t)nh * 384 + 256 + d];
    vt[d * 72 + tl] = v;
  }
  __syncthreads();
#pragma unroll
  for (int i = 0; i < 4; ++i) {
    int c = i * 256 + tid;
    int d = c >> 3, slot = c & 7;
    *(bf16x8*)(Vtb + ((size_t)head * HD + d) * KV + t0 + slot * 8) =
        *(const bf16x8*)(vt + d * 72 + slot * 8);
  }
}

// ---------------- flash attention ----------------
__global__ __launch_bounds__(256) void attn_fwd(const u16* __restrict__ Qb, const u16* __restrict__ Kb,
                                                const u16* __restrict__ Vtb, u16* __restrict__ ctx) {
  __shared__ u16 Ks[64 * 128];
  __shared__ u16 Vts[128 * 64];
  __shared__ u16 Ps[4 * 16 * 64];
  const int tid = threadIdx.x;
  const int lane = tid & 63;
  const int w = tid >> 6;
  const int q0 = blockIdx.x * 64;
  const int head = blockIdx.y;
  const int rl = lane & 15, cg = lane >> 4;

  bf16x8 qf[4];
  {
    const u16* Qrow = Qb + ((size_t)head * SQ + q0 + w * 16 + rl) * HD;
#pragma unroll
    for (int kk = 0; kk < 4; ++kk)
      qf[kk] = *(const bf16x8*)(Qrow + kk * 32 + cg * 8);
  }

  f32x4 acc[8];
#pragma unroll
  for (int i = 0; i < 8; ++i) acc[i] = (f32x4){0.f, 0.f, 0.f, 0.f};
  float mrow[4] = {-3.0e38f, -3.0e38f, -3.0e38f, -3.0e38f};
  float lrow[4] = {0.f, 0.f, 0.f, 0.f};

  const int t_end = q0 + 64 + MEML;

  for (int t0 = 0; t0 < t_end; t0 += 64) {
#pragma unroll
    for (int i = 0; i < 4; ++i) {
      int flat = i * 256 + tid;
      int row = flat >> 4;
      int cb = (flat & 15) << 4;
      int scb = cb ^ ((row & 7) << 4);
      gload_lds16((const char*)(Kb + ((size_t)head * KV + t0 + row) * HD) + scb,
                  (char*)Ks + (flat << 4));
    }
#pragma unroll
    for (int i = 0; i < 4; ++i) {
      int flat = i * 256 + tid;
      int row = flat >> 3;
      int cb = (flat & 7) << 4;
      int scb = cb ^ ((row & 7) << 4);
      gload_lds16((const char*)(Vtb + ((size_t)head * HD + row) * KV + t0) + scb,
                  (char*)Vts + (flat << 4));
    }
    __syncthreads();

    f32x4 sf[4];
#pragma unroll
    for (int tn = 0; tn < 4; ++tn) {
      f32x4 s = (f32x4){0.f, 0.f, 0.f, 0.f};
#pragma unroll
      for (int kk = 0; kk < 4; ++kk) {
        int row = tn * 16 + rl;
        int cb = (kk * 64 + cg * 16) ^ ((row & 7) << 4);
        bf16x8 kf = *(const bf16x8*)((const char*)Ks + row * 256 + cb);
        s = __builtin_amdgcn_mfma_f32_16x16x32_bf16(qf[kk], kf, s, 0, 0, 0);
      }
      sf[tn] = s;
    }
    if (t0 + 63 > MEML + q0 + w * 16) {
#pragma unroll
      for (int tn = 0; tn < 4; ++tn)
#pragma unroll
        for (int j = 0; j < 4; ++j) {
          int t = t0 + tn * 16 + rl;
          int srow = q0 + w * 16 + cg * 4 + j;
          if (t - MEML > srow) sf[tn][j] = -40000.0f;
        }
    }
    float mt[4];
#pragma unroll
    for (int j = 0; j < 4; ++j)
      mt[j] = fmaxf(fmaxf(sf[0][j], sf[1][j]), fmaxf(sf[2][j], sf[3][j]));
#pragma unroll
    for (int off = 1; off <= 8; off <<= 1)
#pragma unroll
      for (int j = 0; j < 4; ++j) mt[j] = fmaxf(mt[j], __shfl_xor(mt[j], off, 64));
    float pscale[4];
#pragma unroll
    for (int j = 0; j < 4; ++j) {
      float mn = fmaxf(mrow[j], mt[j]);
      pscale[j] = __expf(mrow[j] - mn);
      mrow[j] = mn;
    }
    float lsum[4] = {0.f, 0.f, 0.f, 0.f};
#pragma unroll
    for (int tn = 0; tn < 4; ++tn)
#pragma unroll
      for (int j = 0; j < 4; ++j) {
        float p = __expf(sf[tn][j] - mrow[j]);
        lsum[j] += p;
        int prow = cg * 4 + j;
        int colb = (tn * 16 + rl) * 2;
        int addr = w * 2048 + prow * 128 + (colb ^ ((prow & 7) << 4));
        *(u16*)((char*)Ps + addr) = f32_to_bf16(p);
      }
#pragma unroll
    for (int off = 1; off <= 8; off <<= 1)
#pragma unroll
      for (int j = 0; j < 4; ++j) lsum[j] += __shfl_xor(lsum[j], off, 64);
#pragma unroll
    for (int j = 0; j < 4; ++j) lrow[j] = lrow[j] * pscale[j] + lsum[j];
#pragma unroll
    for (int dn = 0; dn < 8; ++dn)
#pragma unroll
      for (int j = 0; j < 4; ++j) acc[dn][j] *= pscale[j];
#pragma unroll
    for (int dn = 0; dn < 8; ++dn) {
#pragma unroll
      for (int kk2 = 0; kk2 < 2; ++kk2) {
        int pcb = (kk2 * 64 + cg * 16) ^ ((rl & 7) << 4);
        bf16x8 pf = *(const bf16x8*)((const char*)Ps + w * 2048 + rl * 128 + pcb);
        int vrow = dn * 16 + rl;
        int vcb = (kk2 * 64 + cg * 16) ^ ((vrow & 7) << 4);
        bf16x8 vf = *(const bf16x8*)((const char*)Vts + vrow * 128 + vcb);
        acc[dn] = __builtin_amdgcn_mfma_f32_16x16x32_bf16(pf, vf, acc[dn], 0, 0, 0);
      }
    }
    __syncthreads();
  }
  const int b = head >> 5, nh = head & 31;
#pragma unroll
  for (int dn = 0; dn < 8; ++dn)
#pragma unroll
    for (int j = 0; j < 4; ++j) {
      int srow = q0 + w * 16 + cg * 4 + j;
      float v = acc[dn][j] / lrow[j];
      ctx[((size_t)(srow * 2 + b)) * H + (size_t)nh * HD + dn * 16 + rl] = f32_to_bf16(v);
    }
}

// ---------------- launch ----------------
extern "C" void kernel_launch(void* const* d_in, const int* in_sizes, int n_in,
                              void* d_out, int out_size, void* d_ws, size_t ws_size,
                              hipStream_t stream) {
  const float* hidden  = (const float*)d_in[0];
  const float* mem     = (const float*)d_in[3];
  const float* qkv_w   = (const float*)d_in[4];
  const float* qkv_b   = (const float*)d_in[5];
  const float* dense_w = (const float*)d_in[6];
  const float* dense_b = (const float*)d_in[7];
  float* out = (float*)d_out;
  char* ws = (char*)d_ws;

  u16* mixed = (u16*)ws;                          // 50,331,648 B used (2048x12288 bf16)
  char* R1 = ws + 100663296;
  u16* hid_bf = (u16*)R1;                         // aliased: pre-GEMM1 use
  u16* qw_bf  = (u16*)(R1 + 16777216);
  u16* Qb  = (u16*)R1;
  u16* Kb  = (u16*)(R1 + 16777216);
  u16* Vtb = (u16*)(R1 + 50331648);
  u16* ctx = (u16*)(R1 + 83886080);
  u16* dw_bf = (u16*)(R1 + 100663296);
  float* cost = (float*)(ws + 234881024);
  float* sint = (float*)(ws + 234881024 + 262144);

  conv_bf16<<<8192, 256, 0, stream>>>(hidden, hid_bf, 2097152);
  conv_bf16<<<49152, 256, 0, stream>>>(qkv_w, qw_bf, 12582912);
  rope_tables<<<256, 256, 0, stream>>>(cost, sint);
  gemmT<u16, 3><<<dim3(64, 8), 512, 0, stream>>>(hid_bf, qw_bf, qkv_b, mixed, 12288, 4096);
  prep_qk<<<dim3(16, 64), 256, 0, stream>>>(mixed, cost, sint, Qb, Kb);
  prep_kv<<<dim3(32, 64), 256, 0, stream>>>(mixed, mem, Kb, Vtb);
  conv_bf16<<<16384, 256, 0, stream>>>(dense_w, dw_bf, 4194304);
  attn_fwd<<<dim3(16, 64), 256, 0, stream>>>(Qb, Kb, Vtb, ctx);
  gemmT<float, 2><<<dim3(32, 8), 512, 0, stream>>>(ctx, dw_bf, dense_b, out, 4096, 4096);
}